// Round 1
// baseline (14707.034 us; speedup 1.0000x reference)
//
#include <hip/hip_runtime.h>
#include <hip/hip_bf16.h>

#define B_SZ   2048
#define T_SZ   256
#define EMB    128
#define NH     256
#define NCLASS 32000

typedef __bf16 bf16;
typedef __bf16 bf16x8 __attribute__((ext_vector_type(8)));
typedef float  f32x4  __attribute__((ext_vector_type(4)));

__device__ __forceinline__ float sigf(float x)      { return 1.0f / (1.0f + __expf(-x)); }
__device__ __forceinline__ float tanhfast(float x)  { return 2.0f / (1.0f + __expf(-2.0f * x)) - 1.0f; }

struct GatePtrs {
    const float* U1[4];  // [EMB][NH]
    const float* V1[4];  // [NH][NH]
    const float* U2[4];  // [NH][NH]
    const float* V2[4];  // [NH][NH]
};

// Gate-column layout: gc = nhgrp*64 + gate*16 + c ; nh = nhgrp*16 + c ; gate 0=i,1=f,2=c,3=o
// Wt1[gc][k] k in [0,384): k<128 -> U_g1[k][nh], else V_g1[k-128][nh]
__global__ void prep_w1(GatePtrs gp, bf16* __restrict__ Wt1) {
    int gc = blockIdx.x;          // 0..1023
    int k  = threadIdx.x;         // 0..383
    int g  = (gc >> 4) & 3;
    int nh = ((gc >> 6) << 4) | (gc & 15);
    float v = (k < EMB) ? gp.U1[g][k * NH + nh] : gp.V1[g][(k - EMB) * NH + nh];
    Wt1[gc * 384 + k] = (bf16)v;
}

// Wt2[gc][k] k in [0,512): k<256 -> U_g2[k][nh] (h1n), else V_g2[k-256][nh] (h2)
__global__ void prep_w2(GatePtrs gp, bf16* __restrict__ Wt2) {
    int gc = blockIdx.x;
    int k  = threadIdx.x;         // 0..511
    int g  = (gc >> 4) & 3;
    int nh = ((gc >> 6) << 4) | (gc & 15);
    float v = (k < NH) ? gp.U2[g][k * NH + nh] : gp.V2[g][(k - NH) * NH + nh];
    Wt2[gc * 512 + k] = (bf16)v;
}

// W_out [NH][NCLASS] fp32 -> WoT [NCLASS][NH] bf16 (B-operand layout), LDS tile transpose
__global__ void prep_wo(const float* __restrict__ Wo, bf16* __restrict__ WoT) {
    __shared__ float tile[32][33];
    int n0 = blockIdx.x * 32;     // 1000 blocks
    int k0 = blockIdx.y * 32;     // 8 blocks
    int tx = threadIdx.x & 31;
    int ty = threadIdx.x >> 5;    // 0..7
#pragma unroll
    for (int i = 0; i < 4; i++) {
        int k = k0 + ty + i * 8;
        tile[ty + i * 8][tx] = Wo[(size_t)k * NCLASS + n0 + tx];
    }
    __syncthreads();
#pragma unroll
    for (int i = 0; i < 4; i++) {
        int n = n0 + ty + i * 8;
        WoT[(size_t)n * NH + k0 + tx] = (bf16)tile[tx][ty + i * 8];
    }
}

// Persistent batch-parallel 2-layer LSTM.
// 64 WGs x 32 batch rows, 512 threads (8 waves). Wave wv owns nh cols [wv*32, wv*32+32)
// across all 4 gates (16 MFMA tiles per layer: 2 M-tiles x 2 nh-groups x 4 gates).
// A1 LDS: [x_t (0..128) | h1 (128..384)] bf16, pad to 392.
// A2 LDS: [h1n (0..256) | h2 (256..512)] bf16, pad to 520.
__global__ __launch_bounds__(512, 1) void lstm_kernel(
    const int* __restrict__ X, const float* __restrict__ C,
    const bf16* __restrict__ Wt1, const bf16* __restrict__ Wt2,
    const float* __restrict__ bi, const float* __restrict__ bf_,
    const float* __restrict__ bc, const float* __restrict__ bo,
    bf16* __restrict__ h2out)
{
    __shared__ bf16 A1[32][392];
    __shared__ bf16 A2[32][520];

    const int tid  = threadIdx.x;
    const int lane = tid & 63;
    const int wv   = tid >> 6;     // 0..7
    const int cl   = lane & 15;    // MFMA col / A-row lane
    const int quad = lane >> 4;    // 0..3
    const int gb   = blockIdx.x * 32;

    // bias regs: layer2 reuses layer1 biases (reference quirk)
    const float* bp[4] = { bi, bf_, bc, bo };
    float bias[2][4];
#pragma unroll
    for (int hg = 0; hg < 2; hg++)
#pragma unroll
        for (int g = 0; g < 4; g++)
            bias[hg][g] = bp[g][wv * 32 + hg * 16 + cl];

    // zero h1 region of A1 and h2 region of A2 (initial state = 0)
    for (int i = tid; i < 8192; i += 512) {
        int r = i >> 8, c = i & 255;
        A1[r][128 + c] = (bf16)0.0f;
        A2[r][256 + c] = (bf16)0.0f;
    }
    // gather x_0
    {
        int r  = tid >> 4;
        int cc = (tid & 15) * 8;
        int idx = X[(gb + r) * T_SZ + 0];
        const float* src = C + (size_t)idx * EMB + cc;
        float4 v0 = *(const float4*)(src);
        float4 v1 = *(const float4*)(src + 4);
        bf16x8 hv;
        hv[0] = (bf16)v0.x; hv[1] = (bf16)v0.y; hv[2] = (bf16)v0.z; hv[3] = (bf16)v0.w;
        hv[4] = (bf16)v1.x; hv[5] = (bf16)v1.y; hv[6] = (bf16)v1.z; hv[7] = (bf16)v1.w;
        *(bf16x8*)&A1[r][cc] = hv;
    }

    f32x4 c1s[2][2], c2s[2][2];
    const f32x4 zf = { 0.0f, 0.0f, 0.0f, 0.0f };
#pragma unroll
    for (int a = 0; a < 2; a++)
#pragma unroll
        for (int b = 0; b < 2; b++) { c1s[a][b] = zf; c2s[a][b] = zf; }

    __syncthreads();

    for (int t = 0; t < T_SZ; t++) {
        // ---------------- layer 1: gates1 = [x|h1] @ Wt1 ----------------
        f32x4 acc[2][2][4];
#pragma unroll
        for (int mt = 0; mt < 2; mt++)
#pragma unroll
            for (int hg = 0; hg < 2; hg++)
#pragma unroll
                for (int g = 0; g < 4; g++) acc[mt][hg][g] = zf;

#pragma unroll
        for (int kt = 0; kt < 12; kt++) {
            bf16x8 a0 = *(const bf16x8*)&A1[cl][kt * 32 + quad * 8];
            bf16x8 a1 = *(const bf16x8*)&A1[16 + cl][kt * 32 + quad * 8];
#pragma unroll
            for (int hg = 0; hg < 2; hg++)
#pragma unroll
                for (int g = 0; g < 4; g++) {
                    int gc = (wv * 2 + hg) * 64 + g * 16 + cl;
                    bf16x8 b = *(const bf16x8*)(Wt1 + gc * 384 + kt * 32 + quad * 8);
                    acc[0][hg][g] = __builtin_amdgcn_mfma_f32_16x16x32_bf16(a0, b, acc[0][hg][g], 0, 0, 0);
                    acc[1][hg][g] = __builtin_amdgcn_mfma_f32_16x16x32_bf16(a1, b, acc[1][hg][g], 0, 0, 0);
                }
        }
        __syncthreads();  // all A1 reads done

        // epilogue 1: gates -> c1,h1n ; write h1n to A1(h1) and A2(h1n)
#pragma unroll
        for (int mt = 0; mt < 2; mt++)
#pragma unroll
            for (int hg = 0; hg < 2; hg++)
#pragma unroll
                for (int r = 0; r < 4; r++) {
                    float iv = sigf(acc[mt][hg][0][r] + bias[hg][0]);
                    float fv = sigf(acc[mt][hg][1][r] + bias[hg][1]);
                    float gv = tanhfast(acc[mt][hg][2][r] + bias[hg][2]);
                    float ov = sigf(acc[mt][hg][3][r] + bias[hg][3]);
                    float c  = c1s[mt][hg][r] * fv + iv * gv;
                    c1s[mt][hg][r] = c;
                    float h  = ov * tanhfast(c);
                    int row = mt * 16 + quad * 4 + r;
                    int col = wv * 32 + hg * 16 + cl;
                    bf16 hb = (bf16)h;
                    A1[row][128 + col] = hb;
                    A2[row][col]       = hb;
                }

        // prefetch-gather x_{t+1}
        if (t + 1 < T_SZ) {
            int r  = tid >> 4;
            int cc = (tid & 15) * 8;
            int idx = X[(gb + r) * T_SZ + (t + 1)];
            const float* src = C + (size_t)idx * EMB + cc;
            float4 v0 = *(const float4*)(src);
            float4 v1 = *(const float4*)(src + 4);
            bf16x8 hv;
            hv[0] = (bf16)v0.x; hv[1] = (bf16)v0.y; hv[2] = (bf16)v0.z; hv[3] = (bf16)v0.w;
            hv[4] = (bf16)v1.x; hv[5] = (bf16)v1.y; hv[6] = (bf16)v1.z; hv[7] = (bf16)v1.w;
            *(bf16x8*)&A1[r][cc] = hv;
        }
        __syncthreads();  // h1n visible in A2; A1 ready for next step

        // ---------------- layer 2: gates2 = [h1n|h2] @ Wt2 ----------------
#pragma unroll
        for (int mt = 0; mt < 2; mt++)
#pragma unroll
            for (int hg = 0; hg < 2; hg++)
#pragma unroll
                for (int g = 0; g < 4; g++) acc[mt][hg][g] = zf;

#pragma unroll
        for (int kt = 0; kt < 16; kt++) {
            bf16x8 a0 = *(const bf16x8*)&A2[cl][kt * 32 + quad * 8];
            bf16x8 a1 = *(const bf16x8*)&A2[16 + cl][kt * 32 + quad * 8];
#pragma unroll
            for (int hg = 0; hg < 2; hg++)
#pragma unroll
                for (int g = 0; g < 4; g++) {
                    int gc = (wv * 2 + hg) * 64 + g * 16 + cl;
                    bf16x8 b = *(const bf16x8*)(Wt2 + gc * 512 + kt * 32 + quad * 8);
                    acc[0][hg][g] = __builtin_amdgcn_mfma_f32_16x16x32_bf16(a0, b, acc[0][hg][g], 0, 0, 0);
                    acc[1][hg][g] = __builtin_amdgcn_mfma_f32_16x16x32_bf16(a1, b, acc[1][hg][g], 0, 0, 0);
                }
        }
        __syncthreads();  // all A2 reads done

        // epilogue 2: c2,h2n ; write h2n to A2(h2)
#pragma unroll
        for (int mt = 0; mt < 2; mt++)
#pragma unroll
            for (int hg = 0; hg < 2; hg++)
#pragma unroll
                for (int r = 0; r < 4; r++) {
                    float iv = sigf(acc[mt][hg][0][r] + bias[hg][0]);
                    float fv = sigf(acc[mt][hg][1][r] + bias[hg][1]);
                    float gv = tanhfast(acc[mt][hg][2][r] + bias[hg][2]);
                    float ov = sigf(acc[mt][hg][3][r] + bias[hg][3]);
                    float c  = c2s[mt][hg][r] * fv + iv * gv;
                    c2s[mt][hg][r] = c;
                    float h  = ov * tanhfast(c);
                    int row = mt * 16 + quad * 4 + r;
                    int col = wv * 32 + hg * 16 + cl;
                    A2[row][256 + col] = (bf16)h;
                }
        // next iteration: layer1 reads A1 (stable since barrier 2); h2n reads only after 2 more barriers
    }

    __syncthreads();
    // export h2 (bf16) for the output GEMM
    for (int i = tid; i < 8192; i += 512) {
        int r = i >> 8, c = i & 255;
        h2out[(size_t)(gb + r) * NH + c] = A2[r][256 + c];
    }
}

// out[2048][32000] = h2 @ W_out + b_out.  Tile: WG 64(M) x 64(N), wave = 16(M) x 64(N).
__global__ __launch_bounds__(256, 1) void out_gemm(
    const bf16* __restrict__ h2, const bf16* __restrict__ WoT,
    const float* __restrict__ bout, float* __restrict__ out)
{
    const int tid  = threadIdx.x;
    const int lane = tid & 63;
    const int wv   = tid >> 6;    // 0..3
    const int cl   = lane & 15;
    const int quad = lane >> 4;
    const int nb   = blockIdx.x;  // 0..499
    const int mb   = blockIdx.y;  // 0..31
    const int mbase = mb * 64 + wv * 16;
    const int nbase = nb * 64;

    f32x4 acc[4];
    const f32x4 zf = { 0.0f, 0.0f, 0.0f, 0.0f };
#pragma unroll
    for (int nt = 0; nt < 4; nt++) acc[nt] = zf;

#pragma unroll
    for (int kt = 0; kt < 8; kt++) {
        bf16x8 a = *(const bf16x8*)(h2 + (size_t)(mbase + cl) * NH + kt * 32 + quad * 8);
#pragma unroll
        for (int nt = 0; nt < 4; nt++) {
            bf16x8 b = *(const bf16x8*)(WoT + (size_t)(nbase + nt * 16 + cl) * NH + kt * 32 + quad * 8);
            acc[nt] = __builtin_amdgcn_mfma_f32_16x16x32_bf16(a, b, acc[nt], 0, 0, 0);
        }
    }
#pragma unroll
    for (int nt = 0; nt < 4; nt++) {
        int col = nbase + nt * 16 + cl;
        float bv = bout[col];
#pragma unroll
        for (int r = 0; r < 4; r++) {
            int row = mbase + quad * 4 + r;
            out[(size_t)row * NCLASS + col] = acc[nt][r] + bv;
        }
    }
}

extern "C" void kernel_launch(void* const* d_in, const int* in_sizes, int n_in,
                              void* d_out, int out_size, void* d_ws, size_t ws_size,
                              hipStream_t stream) {
    const int*   X  = (const int*)d_in[0];
    const float* C  = (const float*)d_in[1];
    GatePtrs gp;
    for (int g = 0; g < 4; g++) {          // gate order i,f,c,o -> input groups at 2+5g
        int base = 2 + 5 * g;
        gp.U1[g] = (const float*)d_in[base + 0];
        gp.V1[g] = (const float*)d_in[base + 1];
        gp.U2[g] = (const float*)d_in[base + 2];
        gp.V2[g] = (const float*)d_in[base + 3];
    }
    const float* bi   = (const float*)d_in[6];
    const float* bf_  = (const float*)d_in[11];
    const float* bc   = (const float*)d_in[16];
    const float* bo   = (const float*)d_in[21];
    const float* Wo   = (const float*)d_in[22];
    const float* bout = (const float*)d_in[23];
    float* out = (float*)d_out;

    char* ws = (char*)d_ws;
    bf16* Wt1 = (bf16*)(ws);                                    // 1024*384*2 = 786432
    bf16* Wt2 = (bf16*)(ws + 786432);                           // 1024*512*2 = 1048576
    bf16* WoT = (bf16*)(ws + 786432 + 1048576);                 // 32000*256*2 = 16384000
    bf16* h2w = (bf16*)(ws + 786432 + 1048576 + 16384000);      // 2048*256*2  = 1048576

    prep_w1<<<dim3(1024), dim3(384), 0, stream>>>(gp, Wt1);
    prep_w2<<<dim3(1024), dim3(512), 0, stream>>>(gp, Wt2);
    prep_wo<<<dim3(1000, 8), dim3(256), 0, stream>>>(Wo, WoT);
    lstm_kernel<<<dim3(64), dim3(512), 0, stream>>>(X, C, Wt1, Wt2, bi, bf_, bc, bo, h2w);
    out_gemm<<<dim3(500, 32), dim3(256), 0, stream>>>(h2w, WoT, bout, out);
}